// Round 9
// baseline (9394.885 us; speedup 1.0000x reference)
//
#include <hip/hip_runtime.h>
#include <hip/hip_cooperative_groups.h>

namespace cg = cooperative_groups;

#define F_IN 16
#define HID 64
#define ITERS 50
#define COST_OFFSET 4.0f
#define SCAN_T 1024

struct __align__(8) Rec { float r; int dst; };

// ---------------- mask dtype detection (proved out in round 6) -------------
__global__ void detect_kernel(const unsigned char* __restrict__ m, int N,
                              int* __restrict__ flag) {
    __shared__ int s[256];
    int t = threadIdx.x;
    int acc = 0;
    for (int i = t; i < N; i += 256) acc += (m[i] != 0);
    s[t] = acc;
    __syncthreads();
    for (int w = 128; w > 0; w >>= 1) {
        if (t < w) s[t] += s[t + w];
        __syncthreads();
    }
    if (t == 0) *flag = (s[0] == 1) ? 1 : 0;
}

// ---------------- Encoder: per-edge MLP -> logr (out0), r (out2) -----------
__global__ __launch_bounds__(256) void encoder_kernel(
    const float* __restrict__ X,
    const float* __restrict__ W1,
    const float* __restrict__ b1,
    const float* __restrict__ W2,
    const float* __restrict__ b2,
    float* __restrict__ out_logr,
    float* __restrict__ out_r,
    int E)
{
    int e = blockIdx.x * blockDim.x + threadIdx.x;
    if (e >= E) return;

    float x[F_IN];
    const float4* xv = reinterpret_cast<const float4*>(X + (size_t)e * F_IN);
    #pragma unroll
    for (int i = 0; i < F_IN / 4; ++i) {
        float4 v = xv[i];
        x[4*i+0] = v.x; x[4*i+1] = v.y; x[4*i+2] = v.z; x[4*i+3] = v.w;
    }

    float h[HID];
    #pragma unroll
    for (int j = 0; j < HID; ++j) h[j] = b1[j];

    #pragma unroll
    for (int i = 0; i < F_IN; ++i) {
        float xi = x[i];
        const float* w = W1 + i * HID;
        #pragma unroll
        for (int j = 0; j < HID; ++j) h[j] = fmaf(xi, w[j], h[j]);
    }

    float u = b2[0];
    #pragma unroll
    for (int j = 0; j < HID; ++j) u = fmaf(fmaxf(h[j], 0.0f), W2[j], u);

    float sp = fmaxf(u, 0.0f) + log1pf(expf(-fabsf(u)));   // softplus
    float cost = sp + COST_OFFSET;
    out_logr[e] = -cost;
    out_r[e]    = expf(-cost);
}

// ---------------- CSR build -------------------------------------------------
__global__ __launch_bounds__(256) void zero_kernel(int* __restrict__ p, int n) {
    int i = blockIdx.x * blockDim.x + threadIdx.x;
    if (i < n) p[i] = 0;
}

__global__ __launch_bounds__(256) void hist_kernel(
    const int* __restrict__ src, int* __restrict__ cnt, int E)
{
    int tid = blockIdx.x * blockDim.x + threadIdx.x;
    int stride = gridDim.x * blockDim.x;
    for (int e = tid; e < E; e += stride) atomicAdd(&cnt[src[e]], 1);
}

// single-block exclusive scan, 4 elements/thread — PROVEN in round 7
__global__ __launch_bounds__(SCAN_T) void scan_kernel(
    const int* __restrict__ cnt, int* __restrict__ row,
    int* __restrict__ ofs, int N)
{
    __shared__ int s[SCAN_T];
    int t = threadIdx.x;
    int running = 0;
    for (int base = 0; base < N; base += SCAN_T * 4) {
        int i0 = base + t * 4;
        int a0 = (i0 + 0 < N) ? cnt[i0 + 0] : 0;
        int a1 = (i0 + 1 < N) ? cnt[i0 + 1] : 0;
        int a2 = (i0 + 2 < N) ? cnt[i0 + 2] : 0;
        int a3 = (i0 + 3 < N) ? cnt[i0 + 3] : 0;
        int tsum = a0 + a1 + a2 + a3;
        s[t] = tsum;
        __syncthreads();
        for (int o = 1; o < SCAN_T; o <<= 1) {
            int x = (t >= o) ? s[t - o] : 0;
            __syncthreads();
            s[t] += x;
            __syncthreads();
        }
        int incl  = s[t];
        int total = s[SCAN_T - 1];
        int e = running + incl - tsum;
        if (i0 + 0 < N) { row[i0 + 0] = e; ofs[i0 + 0] = e; } e += a0;
        if (i0 + 1 < N) { row[i0 + 1] = e; ofs[i0 + 1] = e; } e += a1;
        if (i0 + 2 < N) { row[i0 + 2] = e; ofs[i0 + 2] = e; } e += a2;
        if (i0 + 3 < N) { row[i0 + 3] = e; ofs[i0 + 3] = e; }
        running += total;
        __syncthreads();
    }
    if (t == 0) row[N] = running;
}

// scatter into interleaved 8B records — ONE random line per edge
__global__ __launch_bounds__(256) void scatter_kernel(
    const int* __restrict__ src, const int* __restrict__ dst,
    const float* __restrict__ r, int* __restrict__ ofs,
    Rec* __restrict__ recs, int E)
{
    int tid = blockIdx.x * blockDim.x + threadIdx.x;
    int stride = gridDim.x * blockDim.x;
    for (int e = tid; e < E; e += stride) {
        int p = atomicAdd(&ofs[src[e]], 1);
        Rec rc; rc.r = r[e]; rc.dst = dst[e];
        recs[p] = rc;
    }
}

// ---------------- init b-vector / z0 ----------------------------------------
__global__ __launch_bounds__(256) void initz_kernel(
    const unsigned char* __restrict__ m8, const int* __restrict__ m32,
    const int* __restrict__ flag,
    double* __restrict__ bvec, double* __restrict__ z0, int N)
{
    int i = blockIdx.x * blockDim.x + threadIdx.x;
    if (i >= N) return;
    double b = (*flag) ? ((m8[i] != 0) ? 1.0 : 0.0)
                       : ((m32[i] != 0) ? 1.0 : 0.0);
    bvec[i] = b;
    z0[i]   = b;
}

// ---------------- persistent 50-iteration kernel (cooperative) --------------
// Body identical to gather_kernel; grid.sync() between iterations. Each block
// re-reads the same recs slice every iter -> per-XCD L2 stays warm.
__global__ __launch_bounds__(256) void persist_kernel(
    const int* __restrict__ row,
    const Rec* __restrict__ recs,
    double* __restrict__ z0,
    double* __restrict__ z1,
    const double* __restrict__ bvec,
    int N)
{
    cg::grid_group grid = cg::this_grid();
    const long tid   = (long)blockIdx.x * blockDim.x + threadIdx.x;
    const long gsz   = (long)gridDim.x * blockDim.x;
    const long total = 4L * N;
    double* zb[2] = { z0, z1 };

    for (int it = 0; it < ITERS; ++it) {
        const double* zin  = zb[it & 1];
        double*       zout = zb[(it + 1) & 1];
        for (long g = tid; g < total; g += gsz) {
            int node = (int)(g >> 2);
            int sub  = (int)(g & 3);
            int beg = row[node], end = row[node + 1];
            double acc = 0.0;
            for (int k = beg + sub; k < end; k += 4) {
                Rec rc = recs[k];
                acc += (double)rc.r * zin[rc.dst];
            }
            acc += __shfl_down(acc, 2, 4);
            acc += __shfl_down(acc, 1, 4);
            if (sub == 0) zout[node] = bvec[node] + acc;
        }
        grid.sync();
    }
}

// ---------------- fallback per-iteration gather (round-8 proven) ------------
__global__ __launch_bounds__(256) void gather_kernel(
    const int* __restrict__ row,
    const Rec* __restrict__ recs,
    const double* __restrict__ zin,
    double* __restrict__ zout,
    const double* __restrict__ bvec,
    int N)
{
    int g = blockIdx.x * blockDim.x + threadIdx.x;
    int node = g >> 2;
    int sub  = g & 3;
    if (node >= N) return;

    int beg = row[node], end = row[node + 1];
    double acc = 0.0;
    for (int k = beg + sub; k < end; k += 4) {
        Rec rc = recs[k];
        acc += (double)rc.r * zin[rc.dst];
    }
    acc += __shfl_down(acc, 2, 4);
    acc += __shfl_down(acc, 1, 4);
    if (sub == 0) zout[node] = bvec[node] + acc;
}

// ---------------- finals ----------------------------------------------------
__global__ __launch_bounds__(256) void final1_kernel(
    const double* __restrict__ z, float* __restrict__ out_logz, int N)
{
    int i = blockIdx.x * blockDim.x + threadIdx.x;
    if (i < N) out_logz[i] = (float)log(z[i]);
}

__global__ __launch_bounds__(256) void final2_kernel(
    const int* __restrict__ src, const int* __restrict__ dst,
    const float* __restrict__ out_logz,
    float* probs_r, int E)
{
    int e = blockIdx.x * blockDim.x + threadIdx.x;
    if (e >= E) return;
    float rr = probs_r[e];
    float p  = rr * expf(out_logz[dst[e]] - out_logz[src[e]]);
    probs_r[e] = p;
}

// ---------------- launch -----------------------------------------------------
extern "C" void kernel_launch(void* const* d_in, const int* in_sizes, int n_in,
                              void* d_out, int out_size, void* d_ws, size_t ws_size,
                              hipStream_t stream)
{
    const int*           edge_index = (const int*)d_in[0];   // [2, E] = [src; dst]
    const float*         X          = (const float*)d_in[1];
    const unsigned char* mask8      = (const unsigned char*)d_in[2];
    const int*           mask32     = (const int*)d_in[2];
    const float*         W1         = (const float*)d_in[3];
    const float*         b1         = (const float*)d_in[4];
    const float*         W2         = (const float*)d_in[5];
    const float*         b2         = (const float*)d_in[6];

    const int E = in_sizes[0] / 2;
    const int N = in_sizes[2];
    const int* src = edge_index;
    const int* dst = edge_index + E;

    float* out      = (float*)d_out;
    float* out_logr = out;
    float* out_logz = out + E;
    float* out_pr   = out + (size_t)E + N;       // r scratch, then probs

    // --- workspace carve-out ---
    char* ws = (char*)d_ws;
    size_t off = 0;
    auto alloc = [&](size_t bytes) -> char* {
        char* p = ws + off;
        off = (off + bytes + 255) & ~(size_t)255;
        return p;
    };
    int*    flag = (int*)   alloc(4);
    int*    cnt  = (int*)   alloc((size_t)N * 4);
    int*    ofs  = (int*)   alloc((size_t)N * 4);
    int*    row  = (int*)   alloc(((size_t)N + 1) * 4);
    Rec*    recs = (Rec*)   alloc((size_t)E * 8);
    double* bvec = (double*)alloc((size_t)N * 8);
    double* z0   = (double*)alloc((size_t)N * 8);
    double* z1   = (double*)alloc((size_t)N * 8);
    (void)ws_size;

    detect_kernel<<<1, 256, 0, stream>>>(mask8, N, flag);
    encoder_kernel<<<(E + 255) / 256, 256, 0, stream>>>(
        X, W1, b1, W2, b2, out_logr, out_pr, E);

    // ---- CSR build (one-time) ----
    zero_kernel<<<(N + 255) / 256, 256, 0, stream>>>(cnt, N);
    hist_kernel<<<2048, 256, 0, stream>>>(src, cnt, E);
    scan_kernel<<<1, SCAN_T, 0, stream>>>(cnt, row, ofs, N);
    scatter_kernel<<<2048, 256, 0, stream>>>(
        src, dst, out_pr, ofs, recs, E);
    initz_kernel<<<(N + 255) / 256, 256, 0, stream>>>(
        mask8, mask32, flag, bvec, z0, N);

    // ---- 50 iterations: persistent cooperative kernel ----
    int occ = 0;
    hipError_t oerr = hipOccupancyMaxActiveBlocksPerMultiprocessor(
        &occ, persist_kernel, 256, 0);
    if (oerr != hipSuccess || occ < 1) occ = 4;
    int pgrid = occ * 256;                       // 256 CUs on MI355X
    int maxg  = (int)((4L * N + 255) / 256);
    if (pgrid > maxg) pgrid = maxg;              // no point exceeding work

    int Nv = N;
    void* pargs[] = { (void*)&row, (void*)&recs, (void*)&z0, (void*)&z1,
                      (void*)&bvec, (void*)&Nv };
    hipError_t perr = hipLaunchCooperativeKernel(
        (void*)persist_kernel, dim3(pgrid), dim3(256), pargs, 0, stream);

    if (perr != hipSuccess) {
        // fallback: proven 50-launch ping-pong
        double* zb[2] = { z0, z1 };
        const int ggrid = (int)(((size_t)4 * N + 255) / 256);
        for (int k = 0; k < ITERS; ++k) {
            gather_kernel<<<ggrid, 256, 0, stream>>>(
                row, recs, zb[k & 1], zb[(k + 1) & 1], bvec, N);
        }
    }

    // final z is in z0 for even ITERS (last write went to zb[(49+1)&1] = z0)
    final1_kernel<<<(N + 255) / 256, 256, 0, stream>>>(
        z0, out_logz, N);
    final2_kernel<<<(E + 255) / 256, 256, 0, stream>>>(
        src, dst, out_logz, out_pr, E);
}

// Round 10
// 7227.885 us; speedup vs baseline: 1.2998x; 1.2998x over previous
//
#include <hip/hip_runtime.h>

#define F_IN 16
#define HID 64
#define ITERS 50
#define COST_OFFSET 4.0f
#define SCAN_T 1024

struct __align__(8) Rec { float r; int dst; };

// ---------------- mask dtype detection (proved out in round 6) -------------
__global__ void detect_kernel(const unsigned char* __restrict__ m, int N,
                              int* __restrict__ flag) {
    __shared__ int s[256];
    int t = threadIdx.x;
    int acc = 0;
    for (int i = t; i < N; i += 256) acc += (m[i] != 0);
    s[t] = acc;
    __syncthreads();
    for (int w = 128; w > 0; w >>= 1) {
        if (t < w) s[t] += s[t + w];
        __syncthreads();
    }
    if (t == 0) *flag = (s[0] == 1) ? 1 : 0;
}

// ---------------- Encoder: per-edge MLP -> logr (out0), r (out2) -----------
__global__ __launch_bounds__(256) void encoder_kernel(
    const float* __restrict__ X,
    const float* __restrict__ W1,
    const float* __restrict__ b1,
    const float* __restrict__ W2,
    const float* __restrict__ b2,
    float* __restrict__ out_logr,
    float* __restrict__ out_r,
    int E)
{
    int e = blockIdx.x * blockDim.x + threadIdx.x;
    if (e >= E) return;

    float x[F_IN];
    const float4* xv = reinterpret_cast<const float4*>(X + (size_t)e * F_IN);
    #pragma unroll
    for (int i = 0; i < F_IN / 4; ++i) {
        float4 v = xv[i];
        x[4*i+0] = v.x; x[4*i+1] = v.y; x[4*i+2] = v.z; x[4*i+3] = v.w;
    }

    float h[HID];
    #pragma unroll
    for (int j = 0; j < HID; ++j) h[j] = b1[j];

    #pragma unroll
    for (int i = 0; i < F_IN; ++i) {
        float xi = x[i];
        const float* w = W1 + i * HID;
        #pragma unroll
        for (int j = 0; j < HID; ++j) h[j] = fmaf(xi, w[j], h[j]);
    }

    float u = b2[0];
    #pragma unroll
    for (int j = 0; j < HID; ++j) u = fmaf(fmaxf(h[j], 0.0f), W2[j], u);

    float sp = fmaxf(u, 0.0f) + log1pf(expf(-fabsf(u)));   // softplus
    float cost = sp + COST_OFFSET;
    out_logr[e] = -cost;
    out_r[e]    = expf(-cost);
}

// ---------------- CSR build -------------------------------------------------
__global__ __launch_bounds__(256) void zero_kernel(int* __restrict__ p, int n) {
    int i = blockIdx.x * blockDim.x + threadIdx.x;
    if (i < n) p[i] = 0;
}

__global__ __launch_bounds__(256) void hist_kernel(
    const int* __restrict__ src, int* __restrict__ cnt, int E)
{
    int tid = blockIdx.x * blockDim.x + threadIdx.x;
    int stride = gridDim.x * blockDim.x;
    for (int e = tid; e < E; e += stride) atomicAdd(&cnt[src[e]], 1);
}

// single-block exclusive scan, 4 elements/thread — PROVEN in round 7
__global__ __launch_bounds__(SCAN_T) void scan_kernel(
    const int* __restrict__ cnt, int* __restrict__ row,
    int* __restrict__ ofs, int N)
{
    __shared__ int s[SCAN_T];
    int t = threadIdx.x;
    int running = 0;
    for (int base = 0; base < N; base += SCAN_T * 4) {
        int i0 = base + t * 4;
        int a0 = (i0 + 0 < N) ? cnt[i0 + 0] : 0;
        int a1 = (i0 + 1 < N) ? cnt[i0 + 1] : 0;
        int a2 = (i0 + 2 < N) ? cnt[i0 + 2] : 0;
        int a3 = (i0 + 3 < N) ? cnt[i0 + 3] : 0;
        int tsum = a0 + a1 + a2 + a3;
        s[t] = tsum;
        __syncthreads();
        for (int o = 1; o < SCAN_T; o <<= 1) {
            int x = (t >= o) ? s[t - o] : 0;
            __syncthreads();
            s[t] += x;
            __syncthreads();
        }
        int incl  = s[t];
        int total = s[SCAN_T - 1];
        int e = running + incl - tsum;
        if (i0 + 0 < N) { row[i0 + 0] = e; ofs[i0 + 0] = e; } e += a0;
        if (i0 + 1 < N) { row[i0 + 1] = e; ofs[i0 + 1] = e; } e += a1;
        if (i0 + 2 < N) { row[i0 + 2] = e; ofs[i0 + 2] = e; } e += a2;
        if (i0 + 3 < N) { row[i0 + 3] = e; ofs[i0 + 3] = e; }
        running += total;
        __syncthreads();
    }
    if (t == 0) row[N] = running;
}

// scatter into interleaved 8B records — ONE random line per edge
__global__ __launch_bounds__(256) void scatter_kernel(
    const int* __restrict__ src, const int* __restrict__ dst,
    const float* __restrict__ r, int* __restrict__ ofs,
    Rec* __restrict__ recs, int E)
{
    int tid = blockIdx.x * blockDim.x + threadIdx.x;
    int stride = gridDim.x * blockDim.x;
    for (int e = tid; e < E; e += stride) {
        int p = atomicAdd(&ofs[src[e]], 1);
        Rec rc; rc.r = r[e]; rc.dst = dst[e];
        recs[p] = rc;
    }
}

// ---------------- init b-vector / z0 / barrier state ------------------------
__global__ __launch_bounds__(256) void initz_kernel(
    const unsigned char* __restrict__ m8, const int* __restrict__ m32,
    const int* __restrict__ flag,
    double* __restrict__ bvec, double* __restrict__ z0,
    int* __restrict__ bar, int N)
{
    int i = blockIdx.x * blockDim.x + threadIdx.x;
    if (i < 2 && blockIdx.x == 0) bar[i] = 0;    // {count, gen}
    if (i >= N) return;
    double b = (*flag) ? ((m8[i] != 0) ? 1.0 : 0.0)
                       : ((m32[i] != 0) ? 1.0 : 0.0);
    bvec[i] = b;
    z0[i]   = b;
}

// ---------------- hand-rolled grid barrier (device-scope atomics) -----------
// Release fence -> arrival count -> last resets count, fences, bumps gen;
// others spin on gen. __threadfence emits agent-scope wbL2/inv on gfx950,
// giving cross-XCD visibility (same primitive CG grid.sync is built on).
__device__ __forceinline__ void grid_barrier(int* cnt, int* gen, int nb) {
    __syncthreads();
    if (threadIdx.x == 0) {
        __threadfence();                          // release
        int g = atomicAdd(gen, 0);                // read generation pre-arrival
        int a = atomicAdd(cnt, 1);
        if (a == nb - 1) {
            atomicExch(cnt, 0);                   // reset BEFORE gen bump
            __threadfence();
            atomicAdd(gen, 1);
        } else {
            while (atomicAdd(gen, 0) == g) __builtin_amdgcn_s_sleep(8);
        }
        __threadfence();                          // acquire
    }
    __syncthreads();
}

// ---------------- persistent 50-iteration kernel (custom barrier) -----------
__global__ __launch_bounds__(256) void persist_kernel(
    const int* __restrict__ row,
    const Rec* __restrict__ recs,
    double* z0,
    double* z1,
    const double* __restrict__ bvec,
    float* __restrict__ out_logz,
    int* cnt, int* gen,
    int N, int nblocks)
{
    const long tid   = (long)blockIdx.x * blockDim.x + threadIdx.x;
    const long gsz   = (long)gridDim.x * blockDim.x;
    const long total = 4L * N;

    for (int it = 0; it < ITERS; ++it) {
        const double* zin  = (it & 1) ? z1 : z0;
        double*       zout = (it & 1) ? z0 : z1;
        for (long g = tid; g < total; g += gsz) {
            int node = (int)(g >> 2);
            int sub  = (int)(g & 3);
            int beg = row[node], end = row[node + 1];
            double acc = 0.0;
            for (int k = beg + sub; k < end; k += 4) {
                Rec rc = recs[k];
                acc += (double)rc.r * zin[rc.dst];
            }
            acc += __shfl_down(acc, 2, 4);
            acc += __shfl_down(acc, 1, 4);
            if (sub == 0) zout[node] = bvec[node] + acc;
        }
        grid_barrier(cnt, gen, nblocks);
    }
    // epilogue: final z is in z0 (even ITERS); write log z
    for (long i = tid; i < N; i += gsz)
        out_logz[i] = (float)log(z0[i]);
}

// ---------------- fallback per-iteration gather (round-8 proven) ------------
__global__ __launch_bounds__(256) void gather_kernel(
    const int* __restrict__ row,
    const Rec* __restrict__ recs,
    const double* __restrict__ zin,
    double* __restrict__ zout,
    const double* __restrict__ bvec,
    int N)
{
    int g = blockIdx.x * blockDim.x + threadIdx.x;
    int node = g >> 2;
    int sub  = g & 3;
    if (node >= N) return;

    int beg = row[node], end = row[node + 1];
    double acc = 0.0;
    for (int k = beg + sub; k < end; k += 4) {
        Rec rc = recs[k];
        acc += (double)rc.r * zin[rc.dst];
    }
    acc += __shfl_down(acc, 2, 4);
    acc += __shfl_down(acc, 1, 4);
    if (sub == 0) zout[node] = bvec[node] + acc;
}

__global__ __launch_bounds__(256) void final1_kernel(
    const double* __restrict__ z, float* __restrict__ out_logz, int N)
{
    int i = blockIdx.x * blockDim.x + threadIdx.x;
    if (i < N) out_logz[i] = (float)log(z[i]);
}

__global__ __launch_bounds__(256) void final2_kernel(
    const int* __restrict__ src, const int* __restrict__ dst,
    const float* __restrict__ out_logz,
    float* probs_r, int E)
{
    int e = blockIdx.x * blockDim.x + threadIdx.x;
    if (e >= E) return;
    float rr = probs_r[e];
    float p  = rr * expf(out_logz[dst[e]] - out_logz[src[e]]);
    probs_r[e] = p;
}

// ---------------- launch -----------------------------------------------------
extern "C" void kernel_launch(void* const* d_in, const int* in_sizes, int n_in,
                              void* d_out, int out_size, void* d_ws, size_t ws_size,
                              hipStream_t stream)
{
    const int*           edge_index = (const int*)d_in[0];   // [2, E] = [src; dst]
    const float*         X          = (const float*)d_in[1];
    const unsigned char* mask8      = (const unsigned char*)d_in[2];
    const int*           mask32     = (const int*)d_in[2];
    const float*         W1         = (const float*)d_in[3];
    const float*         b1         = (const float*)d_in[4];
    const float*         W2         = (const float*)d_in[5];
    const float*         b2         = (const float*)d_in[6];

    const int E = in_sizes[0] / 2;
    const int N = in_sizes[2];
    const int* src = edge_index;
    const int* dst = edge_index + E;

    float* out      = (float*)d_out;
    float* out_logr = out;
    float* out_logz = out + E;
    float* out_pr   = out + (size_t)E + N;       // r scratch, then probs

    // --- workspace carve-out ---
    char* ws = (char*)d_ws;
    size_t off = 0;
    auto alloc = [&](size_t bytes) -> char* {
        char* p = ws + off;
        off = (off + bytes + 255) & ~(size_t)255;
        return p;
    };
    int*    flag = (int*)   alloc(4);
    int*    bar  = (int*)   alloc(256);          // {count, gen} on own line
    int*    cnt  = (int*)   alloc((size_t)N * 4);
    int*    ofs  = (int*)   alloc((size_t)N * 4);
    int*    row  = (int*)   alloc(((size_t)N + 1) * 4);
    Rec*    recs = (Rec*)   alloc((size_t)E * 8);
    double* bvec = (double*)alloc((size_t)N * 8);
    double* z0   = (double*)alloc((size_t)N * 8);
    double* z1   = (double*)alloc((size_t)N * 8);
    (void)ws_size;

    detect_kernel<<<1, 256, 0, stream>>>(mask8, N, flag);
    encoder_kernel<<<(E + 255) / 256, 256, 0, stream>>>(
        X, W1, b1, W2, b2, out_logr, out_pr, E);

    // ---- CSR build (one-time) ----
    zero_kernel<<<(N + 255) / 256, 256, 0, stream>>>(cnt, N);
    hist_kernel<<<2048, 256, 0, stream>>>(src, cnt, E);
    scan_kernel<<<1, SCAN_T, 0, stream>>>(cnt, row, ofs, N);
    scatter_kernel<<<2048, 256, 0, stream>>>(
        src, dst, out_pr, ofs, recs, E);
    initz_kernel<<<(N + 255) / 256, 256, 0, stream>>>(
        mask8, mask32, flag, bvec, z0, bar, N);

    // ---- 50 iterations: persistent kernel with custom grid barrier ----
    int occ = 0;
    hipError_t oerr = hipOccupancyMaxActiveBlocksPerMultiprocessor(
        &occ, persist_kernel, 256, 0);
    const int maxg = (int)((4L * N + 255) / 256);

    if (oerr == hipSuccess && occ >= 1) {
        int pgrid = occ * 256;                   // co-residency guaranteed
        if (pgrid > 1024) pgrid = 1024;          // cap barrier arrivals
        if (pgrid > maxg) pgrid = maxg;
        persist_kernel<<<pgrid, 256, 0, stream>>>(
            row, recs, z0, z1, bvec, out_logz, bar + 0, bar + 1, N, pgrid);
    } else {
        // fallback: proven 50-launch ping-pong
        double* zb[2] = { z0, z1 };
        for (int k = 0; k < ITERS; ++k) {
            gather_kernel<<<maxg, 256, 0, stream>>>(
                row, recs, zb[k & 1], zb[(k + 1) & 1], bvec, N);
        }
        final1_kernel<<<(N + 255) / 256, 256, 0, stream>>>(z0, out_logz, N);
    }

    final2_kernel<<<(E + 255) / 256, 256, 0, stream>>>(
        src, dst, out_logz, out_pr, E);
}

// Round 11
// 966.810 us; speedup vs baseline: 9.7174x; 7.4760x over previous
//
#include <hip/hip_runtime.h>

#define F_IN 16
#define HID 64
#define ITERS 50
#define COST_OFFSET 4.0f
#define SCAN_T 1024

struct __align__(8) Rec { float r; int dst; };

// ---------------- mask dtype detection (proved out in round 6) -------------
__global__ void detect_kernel(const unsigned char* __restrict__ m, int N,
                              int* __restrict__ flag) {
    __shared__ int s[256];
    int t = threadIdx.x;
    int acc = 0;
    for (int i = t; i < N; i += 256) acc += (m[i] != 0);
    s[t] = acc;
    __syncthreads();
    for (int w = 128; w > 0; w >>= 1) {
        if (t < w) s[t] += s[t + w];
        __syncthreads();
    }
    if (t == 0) *flag = (s[0] == 1) ? 1 : 0;
}

// ---------------- Encoder: per-edge MLP -> logr (out0), r (out2) -----------
__global__ __launch_bounds__(256) void encoder_kernel(
    const float* __restrict__ X,
    const float* __restrict__ W1,
    const float* __restrict__ b1,
    const float* __restrict__ W2,
    const float* __restrict__ b2,
    float* __restrict__ out_logr,
    float* __restrict__ out_r,
    int E)
{
    int e = blockIdx.x * blockDim.x + threadIdx.x;
    if (e >= E) return;

    float x[F_IN];
    const float4* xv = reinterpret_cast<const float4*>(X + (size_t)e * F_IN);
    #pragma unroll
    for (int i = 0; i < F_IN / 4; ++i) {
        float4 v = xv[i];
        x[4*i+0] = v.x; x[4*i+1] = v.y; x[4*i+2] = v.z; x[4*i+3] = v.w;
    }

    float h[HID];
    #pragma unroll
    for (int j = 0; j < HID; ++j) h[j] = b1[j];

    #pragma unroll
    for (int i = 0; i < F_IN; ++i) {
        float xi = x[i];
        const float* w = W1 + i * HID;
        #pragma unroll
        for (int j = 0; j < HID; ++j) h[j] = fmaf(xi, w[j], h[j]);
    }

    float u = b2[0];
    #pragma unroll
    for (int j = 0; j < HID; ++j) u = fmaf(fmaxf(h[j], 0.0f), W2[j], u);

    float sp = fmaxf(u, 0.0f) + log1pf(expf(-fabsf(u)));   // softplus
    float cost = sp + COST_OFFSET;
    out_logr[e] = -cost;
    out_r[e]    = expf(-cost);
}

// ---------------- CSR build -------------------------------------------------
__global__ __launch_bounds__(256) void zero_kernel(int* __restrict__ p, int n) {
    int i = blockIdx.x * blockDim.x + threadIdx.x;
    if (i < n) p[i] = 0;
}

__global__ __launch_bounds__(256) void hist_kernel(
    const int* __restrict__ src, int* __restrict__ cnt, int E)
{
    int tid = blockIdx.x * blockDim.x + threadIdx.x;
    int stride = gridDim.x * blockDim.x;
    for (int e = tid; e < E; e += stride) atomicAdd(&cnt[src[e]], 1);
}

// single-block exclusive scan over EVEN-PADDED row sizes (row starts stay
// 16B-aligned in Rec units); pad slots are pre-zeroed -> contribute r=0.
__global__ __launch_bounds__(SCAN_T) void scan_kernel(
    const int* __restrict__ cnt, int* __restrict__ row,
    int* __restrict__ ofs, int N)
{
    __shared__ int s[SCAN_T];
    int t = threadIdx.x;
    int running = 0;
    for (int base = 0; base < N; base += SCAN_T * 4) {
        int i0 = base + t * 4;
        int c0 = (i0 + 0 < N) ? cnt[i0 + 0] : 0;
        int c1 = (i0 + 1 < N) ? cnt[i0 + 1] : 0;
        int c2 = (i0 + 2 < N) ? cnt[i0 + 2] : 0;
        int c3 = (i0 + 3 < N) ? cnt[i0 + 3] : 0;
        int a0 = c0 + (c0 & 1);                  // pad to even
        int a1 = c1 + (c1 & 1);
        int a2 = c2 + (c2 & 1);
        int a3 = c3 + (c3 & 1);
        int tsum = a0 + a1 + a2 + a3;
        s[t] = tsum;
        __syncthreads();
        for (int o = 1; o < SCAN_T; o <<= 1) {
            int x = (t >= o) ? s[t - o] : 0;
            __syncthreads();
            s[t] += x;
            __syncthreads();
        }
        int incl  = s[t];
        int total = s[SCAN_T - 1];
        int e = running + incl - tsum;
        if (i0 + 0 < N) { row[i0 + 0] = e; ofs[i0 + 0] = e; } e += a0;
        if (i0 + 1 < N) { row[i0 + 1] = e; ofs[i0 + 1] = e; } e += a1;
        if (i0 + 2 < N) { row[i0 + 2] = e; ofs[i0 + 2] = e; } e += a2;
        if (i0 + 3 < N) { row[i0 + 3] = e; ofs[i0 + 3] = e; }
        running += total;
        __syncthreads();
    }
    if (t == 0) row[N] = running;
}

// scatter into interleaved 8B records — ONE random line per edge
__global__ __launch_bounds__(256) void scatter_kernel(
    const int* __restrict__ src, const int* __restrict__ dst,
    const float* __restrict__ r, int* __restrict__ ofs,
    Rec* __restrict__ recs, int E)
{
    int tid = blockIdx.x * blockDim.x + threadIdx.x;
    int stride = gridDim.x * blockDim.x;
    for (int e = tid; e < E; e += stride) {
        int p = atomicAdd(&ofs[src[e]], 1);
        Rec rc; rc.r = r[e]; rc.dst = dst[e];
        recs[p] = rc;
    }
}

// ---------------- init b-vector / z0 ----------------------------------------
__global__ __launch_bounds__(256) void initz_kernel(
    const unsigned char* __restrict__ m8, const int* __restrict__ m32,
    const int* __restrict__ flag,
    double* __restrict__ bvec, double* __restrict__ z0, int N)
{
    int i = blockIdx.x * blockDim.x + threadIdx.x;
    if (i >= N) return;
    double b = (*flag) ? ((m8[i] != 0) ? 1.0 : 0.0)
                       : ((m32[i] != 0) ? 1.0 : 0.0);
    bvec[i] = b;
    z0[i]   = b;
}

// ---------------- gather iteration: 8 lanes/node, paired 16B rec loads ------
__global__ __launch_bounds__(256) void gather8_kernel(
    const int* __restrict__ row,
    const float4* __restrict__ recs4,            // 2 Recs per float4
    const double* __restrict__ zin,
    double* __restrict__ zout,
    const double* __restrict__ bvec,
    float* __restrict__ out_logz,
    int N, int writeLog)
{
    int g = blockIdx.x * blockDim.x + threadIdx.x;
    int node = g >> 3;
    int sub  = g & 7;
    if (node >= N) return;

    int beg = row[node], end = row[node + 1];    // both even
    double acc = 0.0;
    for (int p = (beg >> 1) + sub; p < (end >> 1); p += 8) {
        float4 q = recs4[p];                     // {r0,d0,r1,d1}
        int d0 = __float_as_int(q.y);
        int d1 = __float_as_int(q.w);
        acc += (double)q.x * zin[d0] + (double)q.z * zin[d1];
    }
    acc += __shfl_down(acc, 4, 8);
    acc += __shfl_down(acc, 2, 8);
    acc += __shfl_down(acc, 1, 8);
    if (sub == 0) {
        double v = bvec[node] + acc;
        zout[node] = v;
        if (writeLog) out_logz[node] = (float)log(v);
    }
}

// ---------------- final: edge probs (out2, in-place over r) -----------------
__global__ __launch_bounds__(256) void final2_kernel(
    const int* __restrict__ src, const int* __restrict__ dst,
    const float* __restrict__ out_logz,
    float* probs_r, int E)
{
    int e = blockIdx.x * blockDim.x + threadIdx.x;
    if (e >= E) return;
    float rr = probs_r[e];
    float p  = rr * expf(out_logz[dst[e]] - out_logz[src[e]]);
    probs_r[e] = p;
}

// ---------------- launch -----------------------------------------------------
extern "C" void kernel_launch(void* const* d_in, const int* in_sizes, int n_in,
                              void* d_out, int out_size, void* d_ws, size_t ws_size,
                              hipStream_t stream)
{
    const int*           edge_index = (const int*)d_in[0];   // [2, E] = [src; dst]
    const float*         X          = (const float*)d_in[1];
    const unsigned char* mask8      = (const unsigned char*)d_in[2];
    const int*           mask32     = (const int*)d_in[2];
    const float*         W1         = (const float*)d_in[3];
    const float*         b1         = (const float*)d_in[4];
    const float*         W2         = (const float*)d_in[5];
    const float*         b2         = (const float*)d_in[6];

    const int E = in_sizes[0] / 2;
    const int N = in_sizes[2];
    const int* src = edge_index;
    const int* dst = edge_index + E;

    float* out      = (float*)d_out;
    float* out_logr = out;
    float* out_logz = out + E;
    float* out_pr   = out + (size_t)E + N;       // r scratch, then probs

    // --- workspace carve-out ---
    char* ws = (char*)d_ws;
    size_t off = 0;
    auto alloc = [&](size_t bytes) -> char* {
        char* p = ws + off;
        off = (off + bytes + 255) & ~(size_t)255;
        return p;
    };
    const int RECS = E + N;                      // padded-CSR upper bound
    int*    flag = (int*)   alloc(4);
    int*    cnt  = (int*)   alloc((size_t)N * 4);
    int*    ofs  = (int*)   alloc((size_t)N * 4);
    int*    row  = (int*)   alloc(((size_t)N + 1) * 4);
    Rec*    recs = (Rec*)   alloc((size_t)RECS * 8);
    double* bvec = (double*)alloc((size_t)N * 8);
    double* z0   = (double*)alloc((size_t)N * 8);
    double* z1   = (double*)alloc((size_t)N * 8);
    (void)ws_size;

    detect_kernel<<<1, 256, 0, stream>>>(mask8, N, flag);
    encoder_kernel<<<(E + 255) / 256, 256, 0, stream>>>(
        X, W1, b1, W2, b2, out_logr, out_pr, E);

    // ---- CSR build (one-time) ----
    zero_kernel<<<(N + 255) / 256, 256, 0, stream>>>(cnt, N);
    hist_kernel<<<2048, 256, 0, stream>>>(src, cnt, E);
    scan_kernel<<<1, SCAN_T, 0, stream>>>(cnt, row, ofs, N);
    zero_kernel<<<(2 * RECS + 255) / 256, 256, 0, stream>>>((int*)recs, 2 * RECS);
    scatter_kernel<<<2048, 256, 0, stream>>>(
        src, dst, out_pr, ofs, recs, E);
    initz_kernel<<<(N + 255) / 256, 256, 0, stream>>>(
        mask8, mask32, flag, bvec, z0, N);

    // ---- 50 gather iterations (8 lanes/node), last fuses log z ----
    double* zb[2] = { z0, z1 };
    const int ggrid = (int)((8L * N + 255) / 256);
    for (int k = 0; k < ITERS; ++k) {
        gather8_kernel<<<ggrid, 256, 0, stream>>>(
            row, (const float4*)recs, zb[k & 1], zb[(k + 1) & 1], bvec,
            out_logz, N, (k == ITERS - 1) ? 1 : 0);
    }

    final2_kernel<<<(E + 255) / 256, 256, 0, stream>>>(
        src, dst, out_logz, out_pr, E);
}

// Round 12
// 887.708 us; speedup vs baseline: 10.5833x; 1.0891x over previous
//
#include <hip/hip_runtime.h>

#define F_IN 16
#define HID 64
#define ITERS 50
#define COST_OFFSET 4.0f
#define SCAN_T 1024

struct __align__(8) Rec { float r; int dst; };

// ---------------- mask dtype detection (proved out in round 6) -------------
__global__ void detect_kernel(const unsigned char* __restrict__ m, int N,
                              int* __restrict__ flag) {
    __shared__ int s[256];
    int t = threadIdx.x;
    int acc = 0;
    for (int i = t; i < N; i += 256) acc += (m[i] != 0);
    s[t] = acc;
    __syncthreads();
    for (int w = 128; w > 0; w >>= 1) {
        if (t < w) s[t] += s[t + w];
        __syncthreads();
    }
    if (t == 0) *flag = (s[0] == 1) ? 1 : 0;
}

__global__ __launch_bounds__(256) void zero_kernel(int* __restrict__ p, int n) {
    int i = blockIdx.x * blockDim.x + threadIdx.x;
    if (i < n) p[i] = 0;
}

// ---------------- Encoder + fused src histogram -----------------------------
__global__ __launch_bounds__(256) void encoder_kernel(
    const float* __restrict__ X,
    const float* __restrict__ W1,
    const float* __restrict__ b1,
    const float* __restrict__ W2,
    const float* __restrict__ b2,
    const int* __restrict__ src,
    int* __restrict__ cnt,           // zeroed before; histogram of src
    float* __restrict__ out_logr,
    float* __restrict__ out_r,
    int E)
{
    int e = blockIdx.x * blockDim.x + threadIdx.x;
    if (e >= E) return;

    float x[F_IN];
    const float4* xv = reinterpret_cast<const float4*>(X + (size_t)e * F_IN);
    #pragma unroll
    for (int i = 0; i < F_IN / 4; ++i) {
        float4 v = xv[i];
        x[4*i+0] = v.x; x[4*i+1] = v.y; x[4*i+2] = v.z; x[4*i+3] = v.w;
    }

    float h[HID];
    #pragma unroll
    for (int j = 0; j < HID; ++j) h[j] = b1[j];

    #pragma unroll
    for (int i = 0; i < F_IN; ++i) {
        float xi = x[i];
        const float* w = W1 + i * HID;
        #pragma unroll
        for (int j = 0; j < HID; ++j) h[j] = fmaf(xi, w[j], h[j]);
    }

    float u = b2[0];
    #pragma unroll
    for (int j = 0; j < HID; ++j) u = fmaf(fmaxf(h[j], 0.0f), W2[j], u);

    float sp = fmaxf(u, 0.0f) + log1pf(expf(-fabsf(u)));   // softplus
    float cost = sp + COST_OFFSET;
    out_logr[e] = -cost;
    out_r[e]    = expf(-cost);

    atomicAdd(&cnt[src[e]], 1);       // fused histogram
}

// single-block exclusive scan over EVEN-PADDED row sizes — PROVEN round 11
__global__ __launch_bounds__(SCAN_T) void scan_kernel(
    const int* __restrict__ cnt, int* __restrict__ row,
    int* __restrict__ ofs, int N)
{
    __shared__ int s[SCAN_T];
    int t = threadIdx.x;
    int running = 0;
    for (int base = 0; base < N; base += SCAN_T * 4) {
        int i0 = base + t * 4;
        int c0 = (i0 + 0 < N) ? cnt[i0 + 0] : 0;
        int c1 = (i0 + 1 < N) ? cnt[i0 + 1] : 0;
        int c2 = (i0 + 2 < N) ? cnt[i0 + 2] : 0;
        int c3 = (i0 + 3 < N) ? cnt[i0 + 3] : 0;
        int a0 = c0 + (c0 & 1);
        int a1 = c1 + (c1 & 1);
        int a2 = c2 + (c2 & 1);
        int a3 = c3 + (c3 & 1);
        int tsum = a0 + a1 + a2 + a3;
        s[t] = tsum;
        __syncthreads();
        for (int o = 1; o < SCAN_T; o <<= 1) {
            int x = (t >= o) ? s[t - o] : 0;
            __syncthreads();
            s[t] += x;
            __syncthreads();
        }
        int incl  = s[t];
        int total = s[SCAN_T - 1];
        int e = running + incl - tsum;
        if (i0 + 0 < N) { row[i0 + 0] = e; ofs[i0 + 0] = e; } e += a0;
        if (i0 + 1 < N) { row[i0 + 1] = e; ofs[i0 + 1] = e; } e += a1;
        if (i0 + 2 < N) { row[i0 + 2] = e; ofs[i0 + 2] = e; } e += a2;
        if (i0 + 3 < N) { row[i0 + 3] = e; ofs[i0 + 3] = e; }
        running += total;
        __syncthreads();
    }
    if (t == 0) row[N] = running;
}

// XCD-partitioned scatter: range j handled only by blocks with blockIdx&7==j,
// confining each XCD's random writes to a private 1.6MB window (L2 line
// reuse before writeback). Every edge processed exactly once regardless of
// the actual blockIdx->XCD mapping.
__global__ __launch_bounds__(256) void scatter_kernel(
    const int* __restrict__ src, const int* __restrict__ dst,
    const float* __restrict__ r, int* __restrict__ ofs,
    Rec* __restrict__ recs, int E, int N)
{
    int part  = blockIdx.x & 7;
    int bslot = blockIdx.x >> 3;
    int nbs   = gridDim.x >> 3;
    int lo = (int)(((long)part * N) >> 3);
    int hi = (int)(((long)(part + 1) * N) >> 3);
    int tid = bslot * blockDim.x + threadIdx.x;
    int stride = nbs * blockDim.x;
    for (int e = tid; e < E; e += stride) {
        int s = src[e];
        if (s >= lo && s < hi) {
            int p = atomicAdd(&ofs[s], 1);
            Rec rc; rc.r = r[e]; rc.dst = dst[e];
            recs[p] = rc;
        }
    }
}

// ---------------- init b-vector / z0 / pad-slot zero ------------------------
__global__ __launch_bounds__(256) void initz_kernel(
    const unsigned char* __restrict__ m8, const int* __restrict__ m32,
    const int* __restrict__ flag,
    const int* __restrict__ cnt, const int* __restrict__ row,
    Rec* __restrict__ recs,
    double* __restrict__ bvec, double* __restrict__ z0, int N)
{
    int i = blockIdx.x * blockDim.x + threadIdx.x;
    if (i >= N) return;
    double b = (*flag) ? ((m8[i] != 0) ? 1.0 : 0.0)
                       : ((m32[i] != 0) ? 1.0 : 0.0);
    bvec[i] = b;
    z0[i]   = b;
    int c = cnt[i];
    if (c & 1) {                      // zero the single pad slot of odd rows
        Rec zr; zr.r = 0.0f; zr.dst = 0;
        recs[row[i] + c] = zr;
    }
}

// ---------------- gather: 4 lanes/node, 2 independent float4 pairs ----------
__global__ __launch_bounds__(256) void gather4_kernel(
    const int* __restrict__ row,
    const float4* __restrict__ recs4,            // 2 Recs per float4
    const double* __restrict__ zin,
    double* __restrict__ zout,
    const double* __restrict__ bvec,
    float* __restrict__ out_logz,
    int N, int writeLog)
{
    int g = blockIdx.x * blockDim.x + threadIdx.x;
    int node = g >> 2;
    int sub  = g & 3;
    if (node >= N) return;

    int pbeg = row[node] >> 1, pend = row[node + 1] >> 1;
    double acc = 0.0;
    int p0 = pbeg + sub;
    while (p0 < pend) {
        int p1 = p0 + 4;
        float4 q0 = recs4[p0];
        if (p1 < pend) {
            float4 q1 = recs4[p1];               // independent second load
            acc += (double)q0.x * zin[__float_as_int(q0.y)]
                 + (double)q0.z * zin[__float_as_int(q0.w)]
                 + (double)q1.x * zin[__float_as_int(q1.y)]
                 + (double)q1.z * zin[__float_as_int(q1.w)];
        } else {
            acc += (double)q0.x * zin[__float_as_int(q0.y)]
                 + (double)q0.z * zin[__float_as_int(q0.w)];
        }
        p0 += 8;
    }
    acc += __shfl_down(acc, 2, 4);
    acc += __shfl_down(acc, 1, 4);
    if (sub == 0) {
        double v = bvec[node] + acc;
        zout[node] = v;
        if (writeLog) out_logz[node] = (float)log(v);
    }
}

// ---------------- final: edge probs (out2, in-place over r) -----------------
__global__ __launch_bounds__(256) void final2_kernel(
    const int* __restrict__ src, const int* __restrict__ dst,
    const float* __restrict__ out_logz,
    float* probs_r, int E)
{
    int e = blockIdx.x * blockDim.x + threadIdx.x;
    if (e >= E) return;
    float rr = probs_r[e];
    float p  = rr * expf(out_logz[dst[e]] - out_logz[src[e]]);
    probs_r[e] = p;
}

// ---------------- launch -----------------------------------------------------
extern "C" void kernel_launch(void* const* d_in, const int* in_sizes, int n_in,
                              void* d_out, int out_size, void* d_ws, size_t ws_size,
                              hipStream_t stream)
{
    const int*           edge_index = (const int*)d_in[0];   // [2, E] = [src; dst]
    const float*         X          = (const float*)d_in[1];
    const unsigned char* mask8      = (const unsigned char*)d_in[2];
    const int*           mask32     = (const int*)d_in[2];
    const float*         W1         = (const float*)d_in[3];
    const float*         b1         = (const float*)d_in[4];
    const float*         W2         = (const float*)d_in[5];
    const float*         b2         = (const float*)d_in[6];

    const int E = in_sizes[0] / 2;
    const int N = in_sizes[2];
    const int* src = edge_index;
    const int* dst = edge_index + E;

    float* out      = (float*)d_out;
    float* out_logr = out;
    float* out_logz = out + E;
    float* out_pr   = out + (size_t)E + N;       // r scratch, then probs

    // --- workspace carve-out ---
    char* ws = (char*)d_ws;
    size_t off = 0;
    auto alloc = [&](size_t bytes) -> char* {
        char* p = ws + off;
        off = (off + bytes + 255) & ~(size_t)255;
        return p;
    };
    const int RECS = E + N;                      // padded-CSR upper bound
    int*    flag = (int*)   alloc(4);
    int*    cnt  = (int*)   alloc((size_t)N * 4);
    int*    ofs  = (int*)   alloc((size_t)N * 4);
    int*    row  = (int*)   alloc(((size_t)N + 1) * 4);
    Rec*    recs = (Rec*)   alloc((size_t)RECS * 8);
    double* bvec = (double*)alloc((size_t)N * 8);
    double* z0   = (double*)alloc((size_t)N * 8);
    double* z1   = (double*)alloc((size_t)N * 8);
    (void)ws_size;

    detect_kernel<<<1, 256, 0, stream>>>(mask8, N, flag);
    zero_kernel<<<(N + 255) / 256, 256, 0, stream>>>(cnt, N);
    encoder_kernel<<<(E + 255) / 256, 256, 0, stream>>>(
        X, W1, b1, W2, b2, src, cnt, out_logr, out_pr, E);

    // ---- CSR build ----
    scan_kernel<<<1, SCAN_T, 0, stream>>>(cnt, row, ofs, N);
    initz_kernel<<<(N + 255) / 256, 256, 0, stream>>>(
        mask8, mask32, flag, cnt, row, recs, bvec, z0, N);
    scatter_kernel<<<2048, 256, 0, stream>>>(
        src, dst, out_pr, ofs, recs, E, N);

    // ---- 50 gather iterations (4 lanes/node, dual-pair ILP) ----
    double* zb[2] = { z0, z1 };
    const int ggrid = (int)((4L * N + 255) / 256);
    for (int k = 0; k < ITERS; ++k) {
        gather4_kernel<<<ggrid, 256, 0, stream>>>(
            row, (const float4*)recs, zb[k & 1], zb[(k + 1) & 1], bvec,
            out_logz, N, (k == ITERS - 1) ? 1 : 0);
    }

    final2_kernel<<<(E + 255) / 256, 256, 0, stream>>>(
        src, dst, out_logz, out_pr, E);
}

// Round 13
// 749.199 us; speedup vs baseline: 12.5399x; 1.1849x over previous
//
#include <hip/hip_runtime.h>

#define F_IN 16
#define HID 64
#define ITERS 50
#define COST_OFFSET 4.0f

struct __align__(8) Rec { float r; int dst; };

// ---------------- parallel mask dtype detection ----------------------------
// bool8 mask sums (over bytes) to exactly 1; int32/f32 mask's first N BYTES
// cover only elements [0,N/4) (sink at N-1) -> sum 0. *sum==1 <=> byte mask.
__global__ __launch_bounds__(256) void detect2_kernel(
    const unsigned char* __restrict__ m, int N, int* __restrict__ sum)
{
    __shared__ int s[256];
    int t = threadIdx.x;
    int tid = blockIdx.x * blockDim.x + t;
    int stride = gridDim.x * blockDim.x;
    int acc = 0;
    for (int i = tid; i < N; i += stride) acc += (m[i] != 0);
    s[t] = acc;
    __syncthreads();
    for (int w = 128; w > 0; w >>= 1) {
        if (t < w) s[t] += s[t + w];
        __syncthreads();
    }
    if (t == 0 && s[0]) atomicAdd(sum, s[0]);
}

__global__ __launch_bounds__(256) void zero_kernel(int* __restrict__ p, int n) {
    int i = blockIdx.x * blockDim.x + threadIdx.x;
    if (i < n) p[i] = 0;
}

// ---------------- Encoder + fused src histogram -----------------------------
__global__ __launch_bounds__(256) void encoder_kernel(
    const float* __restrict__ X,
    const float* __restrict__ W1,
    const float* __restrict__ b1,
    const float* __restrict__ W2,
    const float* __restrict__ b2,
    const int* __restrict__ src,
    int* __restrict__ cnt,
    float* __restrict__ out_logr,
    float* __restrict__ out_r,
    int E)
{
    int e = blockIdx.x * blockDim.x + threadIdx.x;
    if (e >= E) return;

    float x[F_IN];
    const float4* xv = reinterpret_cast<const float4*>(X + (size_t)e * F_IN);
    #pragma unroll
    for (int i = 0; i < F_IN / 4; ++i) {
        float4 v = xv[i];
        x[4*i+0] = v.x; x[4*i+1] = v.y; x[4*i+2] = v.z; x[4*i+3] = v.w;
    }

    float h[HID];
    #pragma unroll
    for (int j = 0; j < HID; ++j) h[j] = b1[j];

    #pragma unroll
    for (int i = 0; i < F_IN; ++i) {
        float xi = x[i];
        const float* w = W1 + i * HID;
        #pragma unroll
        for (int j = 0; j < HID; ++j) h[j] = fmaf(xi, w[j], h[j]);
    }

    float u = b2[0];
    #pragma unroll
    for (int j = 0; j < HID; ++j) u = fmaf(fmaxf(h[j], 0.0f), W2[j], u);

    float sp = fmaxf(u, 0.0f) + log1pf(expf(-fabsf(u)));   // softplus
    float cost = sp + COST_OFFSET;
    out_logr[e] = -cost;
    out_r[e]    = expf(-cost);

    atomicAdd(&cnt[src[e]], 1);       // fused histogram
}

// ---------------- multi-block scan over EVEN-PADDED counts ------------------
// 2048 elems per block (256 thr x 8). A: block totals. B: scan totals (1 blk,
// NB<=1024) + row[N]. C: local scan + offset -> row/ofs.
__global__ __launch_bounds__(256) void scanA_kernel(
    const int* __restrict__ cnt, int* __restrict__ partials, int N)
{
    __shared__ int sm[256];
    int t = threadIdx.x;
    int base = blockIdx.x * 2048 + t * 8;
    int s = 0;
    #pragma unroll
    for (int j = 0; j < 8; ++j) {
        int i = base + j;
        int c = (i < N) ? cnt[i] : 0;
        s += c + (c & 1);
    }
    sm[t] = s;
    __syncthreads();
    for (int w = 128; w > 0; w >>= 1) {
        if (t < w) sm[t] += sm[t + w];
        __syncthreads();
    }
    if (t == 0) partials[blockIdx.x] = sm[0];
}

__global__ __launch_bounds__(256) void scanB_kernel(
    int* __restrict__ partials, int* __restrict__ row, int N, int NB)
{
    __shared__ int sm[256];
    int t = threadIdx.x;
    int i0 = t * 4;
    int a0 = (i0 + 0 < NB) ? partials[i0 + 0] : 0;
    int a1 = (i0 + 1 < NB) ? partials[i0 + 1] : 0;
    int a2 = (i0 + 2 < NB) ? partials[i0 + 2] : 0;
    int a3 = (i0 + 3 < NB) ? partials[i0 + 3] : 0;
    int ts = a0 + a1 + a2 + a3;
    sm[t] = ts;
    __syncthreads();
    for (int o = 1; o < 256; o <<= 1) {
        int x = (t >= o) ? sm[t - o] : 0;
        __syncthreads();
        sm[t] += x;
        __syncthreads();
    }
    int ex = sm[t] - ts;
    if (i0 + 0 < NB) partials[i0 + 0] = ex; ex += a0;
    if (i0 + 1 < NB) partials[i0 + 1] = ex; ex += a1;
    if (i0 + 2 < NB) partials[i0 + 2] = ex; ex += a2;
    if (i0 + 3 < NB) partials[i0 + 3] = ex;
    if (t == 255) row[N] = sm[255];
}

__global__ __launch_bounds__(256) void scanC_kernel(
    const int* __restrict__ cnt, const int* __restrict__ partials,
    int* __restrict__ row, int* __restrict__ ofs, int N)
{
    __shared__ int sm[256];
    int t = threadIdx.x;
    int base = blockIdx.x * 2048 + t * 8;
    int vals[8];
    int s = 0;
    #pragma unroll
    for (int j = 0; j < 8; ++j) {
        int i = base + j;
        int c = (i < N) ? cnt[i] : 0;
        vals[j] = c + (c & 1);
        s += vals[j];
    }
    sm[t] = s;
    __syncthreads();
    for (int o = 1; o < 256; o <<= 1) {
        int x = (t >= o) ? sm[t - o] : 0;
        __syncthreads();
        sm[t] += x;
        __syncthreads();
    }
    int ex = sm[t] - s + partials[blockIdx.x];
    #pragma unroll
    for (int j = 0; j < 8; ++j) {
        int i = base + j;
        if (i < N) { row[i] = ex; ofs[i] = ex; }
        ex += vals[j];
    }
}

// XCD-partitioned scatter (proven round 12)
__global__ __launch_bounds__(256) void scatter_kernel(
    const int* __restrict__ src, const int* __restrict__ dst,
    const float* __restrict__ r, int* __restrict__ ofs,
    Rec* __restrict__ recs, int E, int N)
{
    int part  = blockIdx.x & 7;
    int bslot = blockIdx.x >> 3;
    int nbs   = gridDim.x >> 3;
    int lo = (int)(((long)part * N) >> 3);
    int hi = (int)(((long)(part + 1) * N) >> 3);
    int tid = bslot * blockDim.x + threadIdx.x;
    int stride = nbs * blockDim.x;
    for (int e = tid; e < E; e += stride) {
        int s = src[e];
        if (s >= lo && s < hi) {
            int p = atomicAdd(&ofs[s], 1);
            Rec rc; rc.r = r[e]; rc.dst = dst[e];
            recs[p] = rc;
        }
    }
}

// ---------------- init b-vector / z0 / pad-slot zero ------------------------
__global__ __launch_bounds__(256) void initz_kernel(
    const unsigned char* __restrict__ m8, const int* __restrict__ m32,
    const int* __restrict__ msum,
    const int* __restrict__ cnt, const int* __restrict__ row,
    Rec* __restrict__ recs,
    double* __restrict__ bvec, double* __restrict__ z0, int N)
{
    int i = blockIdx.x * blockDim.x + threadIdx.x;
    if (i >= N) return;
    double b = (*msum == 1) ? ((m8[i] != 0) ? 1.0 : 0.0)
                            : ((m32[i] != 0) ? 1.0 : 0.0);
    bvec[i] = b;
    z0[i]   = b;
    int c = cnt[i];
    if (c & 1) {
        Rec zr; zr.r = 0.0f; zr.dst = 0;
        recs[row[i] + c] = zr;
    }
}

// ---------------- gather: 4 lanes/node, dual-pair ILP (proven round 12) -----
__global__ __launch_bounds__(256) void gather4_kernel(
    const int* __restrict__ row,
    const float4* __restrict__ recs4,
    const double* __restrict__ zin,
    double* __restrict__ zout,
    const double* __restrict__ bvec,
    float* __restrict__ out_logz,
    int N, int writeLog)
{
    int g = blockIdx.x * blockDim.x + threadIdx.x;
    int node = g >> 2;
    int sub  = g & 3;
    if (node >= N) return;

    int pbeg = row[node] >> 1, pend = row[node + 1] >> 1;
    double acc = 0.0;
    int p0 = pbeg + sub;
    while (p0 < pend) {
        int p1 = p0 + 4;
        float4 q0 = recs4[p0];
        if (p1 < pend) {
            float4 q1 = recs4[p1];
            acc += (double)q0.x * zin[__float_as_int(q0.y)]
                 + (double)q0.z * zin[__float_as_int(q0.w)]
                 + (double)q1.x * zin[__float_as_int(q1.y)]
                 + (double)q1.z * zin[__float_as_int(q1.w)];
        } else {
            acc += (double)q0.x * zin[__float_as_int(q0.y)]
                 + (double)q0.z * zin[__float_as_int(q0.w)];
        }
        p0 += 8;
    }
    acc += __shfl_down(acc, 2, 4);
    acc += __shfl_down(acc, 1, 4);
    if (sub == 0) {
        double v = bvec[node] + acc;
        zout[node] = v;
        if (writeLog) out_logz[node] = (float)log(v);
    }
}

// ---------------- final: edge probs (out2, in-place over r) -----------------
__global__ __launch_bounds__(256) void final2_kernel(
    const int* __restrict__ src, const int* __restrict__ dst,
    const float* __restrict__ out_logz,
    float* probs_r, int E)
{
    int e = blockIdx.x * blockDim.x + threadIdx.x;
    if (e >= E) return;
    float rr = probs_r[e];
    float p  = rr * expf(out_logz[dst[e]] - out_logz[src[e]]);
    probs_r[e] = p;
}

// ---------------- launch -----------------------------------------------------
extern "C" void kernel_launch(void* const* d_in, const int* in_sizes, int n_in,
                              void* d_out, int out_size, void* d_ws, size_t ws_size,
                              hipStream_t stream)
{
    const int*           edge_index = (const int*)d_in[0];   // [2, E] = [src; dst]
    const float*         X          = (const float*)d_in[1];
    const unsigned char* mask8      = (const unsigned char*)d_in[2];
    const int*           mask32     = (const int*)d_in[2];
    const float*         W1         = (const float*)d_in[3];
    const float*         b1         = (const float*)d_in[4];
    const float*         W2         = (const float*)d_in[5];
    const float*         b2         = (const float*)d_in[6];

    const int E = in_sizes[0] / 2;
    const int N = in_sizes[2];
    const int* src = edge_index;
    const int* dst = edge_index + E;

    float* out      = (float*)d_out;
    float* out_logr = out;
    float* out_logz = out + E;
    float* out_pr   = out + (size_t)E + N;       // r scratch, then probs

    // --- workspace carve-out ---
    char* ws = (char*)d_ws;
    size_t off = 0;
    auto alloc = [&](size_t bytes) -> char* {
        char* p = ws + off;
        off = (off + bytes + 255) & ~(size_t)255;
        return p;
    };
    const int RECS = E + N;
    int*    msum  = (int*)   alloc(4);
    int*    parts = (int*)   alloc(4096);        // block partials (NB<=1024)
    int*    cnt   = (int*)   alloc((size_t)N * 4);
    int*    ofs   = (int*)   alloc((size_t)N * 4);
    int*    row   = (int*)   alloc(((size_t)N + 1) * 4);
    Rec*    recs  = (Rec*)   alloc((size_t)RECS * 8);
    double* bvec  = (double*)alloc((size_t)N * 8);
    double* z0    = (double*)alloc((size_t)N * 8);
    double* z1    = (double*)alloc((size_t)N * 8);
    (void)ws_size;

    hipMemsetAsync(msum, 0, 4, stream);
    detect2_kernel<<<64, 256, 0, stream>>>(mask8, N, msum);
    zero_kernel<<<(N + 255) / 256, 256, 0, stream>>>(cnt, N);
    encoder_kernel<<<(E + 255) / 256, 256, 0, stream>>>(
        X, W1, b1, W2, b2, src, cnt, out_logr, out_pr, E);

    // ---- CSR build: multi-block scan ----
    const int NB = (N + 2047) / 2048;            // <= 1024 for N <= 2M
    scanA_kernel<<<NB, 256, 0, stream>>>(cnt, parts, N);
    scanB_kernel<<<1, 256, 0, stream>>>(parts, row, N, NB);
    scanC_kernel<<<NB, 256, 0, stream>>>(cnt, parts, row, ofs, N);

    initz_kernel<<<(N + 255) / 256, 256, 0, stream>>>(
        mask8, mask32, msum, cnt, row, recs, bvec, z0, N);
    scatter_kernel<<<2048, 256, 0, stream>>>(
        src, dst, out_pr, ofs, recs, E, N);

    // ---- 50 gather iterations ----
    double* zb[2] = { z0, z1 };
    const int ggrid = (int)((4L * N + 255) / 256);
    for (int k = 0; k < ITERS; ++k) {
        gather4_kernel<<<ggrid, 256, 0, stream>>>(
            row, (const float4*)recs, zb[k & 1], zb[(k + 1) & 1], bvec,
            out_logz, N, (k == ITERS - 1) ? 1 : 0);
    }

    final2_kernel<<<(E + 255) / 256, 256, 0, stream>>>(
        src, dst, out_logz, out_pr, E);
}

// Round 14
// 749.091 us; speedup vs baseline: 12.5417x; 1.0001x over previous
//
#include <hip/hip_runtime.h>

#define F_IN 16
#define HID 64
#define ITERS 50
#define COST_OFFSET 4.0f

struct __align__(8) Rec { float r; int dst; };

// ---------------- parallel mask dtype detection ----------------------------
// bool8 mask sums (over bytes) to exactly 1; int32/f32 mask's first N BYTES
// cover only elements [0,N/4) (sink at N-1) -> sum 0. *sum==1 <=> byte mask.
__global__ __launch_bounds__(256) void detect2_kernel(
    const unsigned char* __restrict__ m, int N, int* __restrict__ sum)
{
    __shared__ int s[256];
    int t = threadIdx.x;
    int tid = blockIdx.x * blockDim.x + t;
    int stride = gridDim.x * blockDim.x;
    int acc = 0;
    for (int i = tid; i < N; i += stride) acc += (m[i] != 0);
    s[t] = acc;
    __syncthreads();
    for (int w = 128; w > 0; w >>= 1) {
        if (t < w) s[t] += s[t + w];
        __syncthreads();
    }
    if (t == 0 && s[0]) atomicAdd(sum, s[0]);
}

__global__ __launch_bounds__(256) void zero_kernel(int* __restrict__ p, int n) {
    int i = blockIdx.x * blockDim.x + threadIdx.x;
    if (i < n) p[i] = 0;
}

// ---------------- Encoder + fused src histogram -----------------------------
__global__ __launch_bounds__(256) void encoder_kernel(
    const float* __restrict__ X,
    const float* __restrict__ W1,
    const float* __restrict__ b1,
    const float* __restrict__ W2,
    const float* __restrict__ b2,
    const int* __restrict__ src,
    int* __restrict__ cnt,
    float* __restrict__ out_logr,
    float* __restrict__ out_r,
    int E)
{
    int e = blockIdx.x * blockDim.x + threadIdx.x;
    if (e >= E) return;

    float x[F_IN];
    const float4* xv = reinterpret_cast<const float4*>(X + (size_t)e * F_IN);
    #pragma unroll
    for (int i = 0; i < F_IN / 4; ++i) {
        float4 v = xv[i];
        x[4*i+0] = v.x; x[4*i+1] = v.y; x[4*i+2] = v.z; x[4*i+3] = v.w;
    }

    float h[HID];
    #pragma unroll
    for (int j = 0; j < HID; ++j) h[j] = b1[j];

    #pragma unroll
    for (int i = 0; i < F_IN; ++i) {
        float xi = x[i];
        const float* w = W1 + i * HID;
        #pragma unroll
        for (int j = 0; j < HID; ++j) h[j] = fmaf(xi, w[j], h[j]);
    }

    float u = b2[0];
    #pragma unroll
    for (int j = 0; j < HID; ++j) u = fmaf(fmaxf(h[j], 0.0f), W2[j], u);

    float sp = fmaxf(u, 0.0f) + log1pf(expf(-fabsf(u)));   // softplus
    float cost = sp + COST_OFFSET;
    out_logr[e] = -cost;
    out_r[e]    = expf(-cost);

    atomicAdd(&cnt[src[e]], 1);       // fused histogram
}

// ---------------- multi-block scan over EVEN-PADDED counts ------------------
// 2048 elems per block (256 thr x 8). A: block totals. B: scan totals (1 blk,
// NB<=1024) + row[N]. C: local scan + offset -> row/ofs.
__global__ __launch_bounds__(256) void scanA_kernel(
    const int* __restrict__ cnt, int* __restrict__ partials, int N)
{
    __shared__ int sm[256];
    int t = threadIdx.x;
    int base = blockIdx.x * 2048 + t * 8;
    int s = 0;
    #pragma unroll
    for (int j = 0; j < 8; ++j) {
        int i = base + j;
        int c = (i < N) ? cnt[i] : 0;
        s += c + (c & 1);
    }
    sm[t] = s;
    __syncthreads();
    for (int w = 128; w > 0; w >>= 1) {
        if (t < w) sm[t] += sm[t + w];
        __syncthreads();
    }
    if (t == 0) partials[blockIdx.x] = sm[0];
}

__global__ __launch_bounds__(256) void scanB_kernel(
    int* __restrict__ partials, int* __restrict__ row, int N, int NB)
{
    __shared__ int sm[256];
    int t = threadIdx.x;
    int i0 = t * 4;
    int a0 = (i0 + 0 < NB) ? partials[i0 + 0] : 0;
    int a1 = (i0 + 1 < NB) ? partials[i0 + 1] : 0;
    int a2 = (i0 + 2 < NB) ? partials[i0 + 2] : 0;
    int a3 = (i0 + 3 < NB) ? partials[i0 + 3] : 0;
    int ts = a0 + a1 + a2 + a3;
    sm[t] = ts;
    __syncthreads();
    for (int o = 1; o < 256; o <<= 1) {
        int x = (t >= o) ? sm[t - o] : 0;
        __syncthreads();
        sm[t] += x;
        __syncthreads();
    }
    int ex = sm[t] - ts;
    if (i0 + 0 < NB) partials[i0 + 0] = ex; ex += a0;
    if (i0 + 1 < NB) partials[i0 + 1] = ex; ex += a1;
    if (i0 + 2 < NB) partials[i0 + 2] = ex; ex += a2;
    if (i0 + 3 < NB) partials[i0 + 3] = ex;
    if (t == 255) row[N] = sm[255];
}

__global__ __launch_bounds__(256) void scanC_kernel(
    const int* __restrict__ cnt, const int* __restrict__ partials,
    int* __restrict__ row, int* __restrict__ ofs, int N)
{
    __shared__ int sm[256];
    int t = threadIdx.x;
    int base = blockIdx.x * 2048 + t * 8;
    int vals[8];
    int s = 0;
    #pragma unroll
    for (int j = 0; j < 8; ++j) {
        int i = base + j;
        int c = (i < N) ? cnt[i] : 0;
        vals[j] = c + (c & 1);
        s += vals[j];
    }
    sm[t] = s;
    __syncthreads();
    for (int o = 1; o < 256; o <<= 1) {
        int x = (t >= o) ? sm[t - o] : 0;
        __syncthreads();
        sm[t] += x;
        __syncthreads();
    }
    int ex = sm[t] - s + partials[blockIdx.x];
    #pragma unroll
    for (int j = 0; j < 8; ++j) {
        int i = base + j;
        if (i < N) { row[i] = ex; ofs[i] = ex; }
        ex += vals[j];
    }
}

// XCD-partitioned scatter (proven round 12)
__global__ __launch_bounds__(256) void scatter_kernel(
    const int* __restrict__ src, const int* __restrict__ dst,
    const float* __restrict__ r, int* __restrict__ ofs,
    Rec* __restrict__ recs, int E, int N)
{
    int part  = blockIdx.x & 7;
    int bslot = blockIdx.x >> 3;
    int nbs   = gridDim.x >> 3;
    int lo = (int)(((long)part * N) >> 3);
    int hi = (int)(((long)(part + 1) * N) >> 3);
    int tid = bslot * blockDim.x + threadIdx.x;
    int stride = nbs * blockDim.x;
    for (int e = tid; e < E; e += stride) {
        int s = src[e];
        if (s >= lo && s < hi) {
            int p = atomicAdd(&ofs[s], 1);
            Rec rc; rc.r = r[e]; rc.dst = dst[e];
            recs[p] = rc;
        }
    }
}

// ---------------- init b-vector / z0 / pad-slot zero ------------------------
__global__ __launch_bounds__(256) void initz_kernel(
    const unsigned char* __restrict__ m8, const int* __restrict__ m32,
    const int* __restrict__ msum,
    const int* __restrict__ cnt, const int* __restrict__ row,
    Rec* __restrict__ recs,
    double* __restrict__ bvec, double* __restrict__ z0, int N)
{
    int i = blockIdx.x * blockDim.x + threadIdx.x;
    if (i >= N) return;
    double b = (*msum == 1) ? ((m8[i] != 0) ? 1.0 : 0.0)
                            : ((m32[i] != 0) ? 1.0 : 0.0);
    bvec[i] = b;
    z0[i]   = b;
    int c = cnt[i];
    if (c & 1) {
        Rec zr; zr.r = 0.0f; zr.dst = 0;
        recs[row[i] + c] = zr;
    }
}

// ---------------- gather: 4 lanes/node, dual-pair ILP (proven round 12) -----
__global__ __launch_bounds__(256) void gather4_kernel(
    const int* __restrict__ row,
    const float4* __restrict__ recs4,
    const double* __restrict__ zin,
    double* __restrict__ zout,
    const double* __restrict__ bvec,
    float* __restrict__ out_logz,
    int N, int writeLog)
{
    int g = blockIdx.x * blockDim.x + threadIdx.x;
    int node = g >> 2;
    int sub  = g & 3;
    if (node >= N) return;

    int pbeg = row[node] >> 1, pend = row[node + 1] >> 1;
    double acc = 0.0;
    int p0 = pbeg + sub;
    while (p0 < pend) {
        int p1 = p0 + 4;
        float4 q0 = recs4[p0];
        if (p1 < pend) {
            float4 q1 = recs4[p1];
            acc += (double)q0.x * zin[__float_as_int(q0.y)]
                 + (double)q0.z * zin[__float_as_int(q0.w)]
                 + (double)q1.x * zin[__float_as_int(q1.y)]
                 + (double)q1.z * zin[__float_as_int(q1.w)];
        } else {
            acc += (double)q0.x * zin[__float_as_int(q0.y)]
                 + (double)q0.z * zin[__float_as_int(q0.w)];
        }
        p0 += 8;
    }
    acc += __shfl_down(acc, 2, 4);
    acc += __shfl_down(acc, 1, 4);
    if (sub == 0) {
        double v = bvec[node] + acc;
        zout[node] = v;
        if (writeLog) out_logz[node] = (float)log(v);
    }
}

// ---------------- final: edge probs (out2, in-place over r) -----------------
__global__ __launch_bounds__(256) void final2_kernel(
    const int* __restrict__ src, const int* __restrict__ dst,
    const float* __restrict__ out_logz,
    float* probs_r, int E)
{
    int e = blockIdx.x * blockDim.x + threadIdx.x;
    if (e >= E) return;
    float rr = probs_r[e];
    float p  = rr * expf(out_logz[dst[e]] - out_logz[src[e]]);
    probs_r[e] = p;
}

// ---------------- launch -----------------------------------------------------
extern "C" void kernel_launch(void* const* d_in, const int* in_sizes, int n_in,
                              void* d_out, int out_size, void* d_ws, size_t ws_size,
                              hipStream_t stream)
{
    const int*           edge_index = (const int*)d_in[0];   // [2, E] = [src; dst]
    const float*         X          = (const float*)d_in[1];
    const unsigned char* mask8      = (const unsigned char*)d_in[2];
    const int*           mask32     = (const int*)d_in[2];
    const float*         W1         = (const float*)d_in[3];
    const float*         b1         = (const float*)d_in[4];
    const float*         W2         = (const float*)d_in[5];
    const float*         b2         = (const float*)d_in[6];

    const int E = in_sizes[0] / 2;
    const int N = in_sizes[2];
    const int* src = edge_index;
    const int* dst = edge_index + E;

    float* out      = (float*)d_out;
    float* out_logr = out;
    float* out_logz = out + E;
    float* out_pr   = out + (size_t)E + N;       // r scratch, then probs

    // --- workspace carve-out ---
    char* ws = (char*)d_ws;
    size_t off = 0;
    auto alloc = [&](size_t bytes) -> char* {
        char* p = ws + off;
        off = (off + bytes + 255) & ~(size_t)255;
        return p;
    };
    const int RECS = E + N;
    int*    msum  = (int*)   alloc(4);
    int*    parts = (int*)   alloc(4096);        // block partials (NB<=1024)
    int*    cnt   = (int*)   alloc((size_t)N * 4);
    int*    ofs   = (int*)   alloc((size_t)N * 4);
    int*    row   = (int*)   alloc(((size_t)N + 1) * 4);
    Rec*    recs  = (Rec*)   alloc((size_t)RECS * 8);
    double* bvec  = (double*)alloc((size_t)N * 8);
    double* z0    = (double*)alloc((size_t)N * 8);
    double* z1    = (double*)alloc((size_t)N * 8);
    (void)ws_size;

    hipMemsetAsync(msum, 0, 4, stream);
    detect2_kernel<<<64, 256, 0, stream>>>(mask8, N, msum);
    zero_kernel<<<(N + 255) / 256, 256, 0, stream>>>(cnt, N);
    encoder_kernel<<<(E + 255) / 256, 256, 0, stream>>>(
        X, W1, b1, W2, b2, src, cnt, out_logr, out_pr, E);

    // ---- CSR build: multi-block scan ----
    const int NB = (N + 2047) / 2048;            // <= 1024 for N <= 2M
    scanA_kernel<<<NB, 256, 0, stream>>>(cnt, parts, N);
    scanB_kernel<<<1, 256, 0, stream>>>(parts, row, N, NB);
    scanC_kernel<<<NB, 256, 0, stream>>>(cnt, parts, row, ofs, N);

    initz_kernel<<<(N + 255) / 256, 256, 0, stream>>>(
        mask8, mask32, msum, cnt, row, recs, bvec, z0, N);
    scatter_kernel<<<2048, 256, 0, stream>>>(
        src, dst, out_pr, ofs, recs, E, N);

    // ---- 50 gather iterations ----
    double* zb[2] = { z0, z1 };
    const int ggrid = (int)((4L * N + 255) / 256);
    for (int k = 0; k < ITERS; ++k) {
        gather4_kernel<<<ggrid, 256, 0, stream>>>(
            row, (const float4*)recs, zb[k & 1], zb[(k + 1) & 1], bvec,
            out_logz, N, (k == ITERS - 1) ? 1 : 0);
    }

    final2_kernel<<<(E + 255) / 256, 256, 0, stream>>>(
        src, dst, out_logz, out_pr, E);
}

// Round 15
// 741.720 us; speedup vs baseline: 12.6664x; 1.0099x over previous
//
#include <hip/hip_runtime.h>

#define F_IN 16
#define HID 64
#define ITERS 50
#define COST_OFFSET 4.0f

struct __align__(8) Rec { float r; int dst; };
typedef __attribute__((ext_vector_type(2))) float f32x2;

// ---------------- mask detect + cnt zero (fused) ----------------------------
__global__ __launch_bounds__(256) void detect2_kernel(
    const unsigned char* __restrict__ m, int N,
    int* __restrict__ sum, int* __restrict__ cnt)
{
    __shared__ int s[256];
    int t = threadIdx.x;
    int tid = blockIdx.x * blockDim.x + t;
    int stride = gridDim.x * blockDim.x;
    int acc = 0;
    for (int i = tid; i < N; i += stride) { acc += (m[i] != 0); cnt[i] = 0; }
    s[t] = acc;
    __syncthreads();
    for (int w = 128; w > 0; w >>= 1) {
        if (t < w) s[t] += s[t + w];
        __syncthreads();
    }
    if (t == 0 && s[0]) atomicAdd(sum, s[0]);
}

// ---------------- Encoder (packed f32x2 math) + fused src histogram --------
__global__ __launch_bounds__(256) void encoder_kernel(
    const float* __restrict__ X,
    const float* __restrict__ W1,
    const float* __restrict__ b1,
    const float* __restrict__ W2,
    const float* __restrict__ b2,
    const int* __restrict__ src,
    int* __restrict__ cnt,
    float* __restrict__ out_logr,
    float* __restrict__ out_r,
    int E)
{
    int e = blockIdx.x * blockDim.x + threadIdx.x;
    if (e >= E) return;

    float x[F_IN];
    const float4* xv = reinterpret_cast<const float4*>(X + (size_t)e * F_IN);
    #pragma unroll
    for (int i = 0; i < F_IN / 4; ++i) {
        float4 v = xv[i];
        x[4*i+0] = v.x; x[4*i+1] = v.y; x[4*i+2] = v.z; x[4*i+3] = v.w;
    }

    f32x2 h[HID / 2];
    const f32x2* b1v = reinterpret_cast<const f32x2*>(b1);
    #pragma unroll
    for (int j = 0; j < HID / 2; ++j) h[j] = b1v[j];

    #pragma unroll
    for (int i = 0; i < F_IN; ++i) {
        f32x2 xi; xi.x = x[i]; xi.y = x[i];
        const f32x2* w = reinterpret_cast<const f32x2*>(W1 + i * HID);
        #pragma unroll
        for (int j = 0; j < HID / 2; ++j)
            h[j] = h[j] + xi * w[j];             // v_pk_fma_f32 (contract)
    }

    const f32x2* w2 = reinterpret_cast<const f32x2*>(W2);
    f32x2 z2; z2.x = 0.0f; z2.y = 0.0f;
    f32x2 us = z2;
    #pragma unroll
    for (int j = 0; j < HID / 2; ++j) {
        f32x2 hr;                                 // relu
        hr.x = fmaxf(h[j].x, 0.0f);
        hr.y = fmaxf(h[j].y, 0.0f);
        us = us + hr * w2[j];
    }
    float u = us.x + us.y + b2[0];

    float sp = fmaxf(u, 0.0f) + log1pf(expf(-fabsf(u)));   // softplus
    float cost = sp + COST_OFFSET;
    out_logr[e] = -cost;
    out_r[e]    = expf(-cost);

    atomicAdd(&cnt[src[e]], 1);       // fused histogram
}

// ---------------- multi-block scan over EVEN-PADDED counts ------------------
__global__ __launch_bounds__(256) void scanA_kernel(
    const int* __restrict__ cnt, int* __restrict__ partials, int N)
{
    __shared__ int sm[256];
    int t = threadIdx.x;
    int base = blockIdx.x * 2048 + t * 8;
    int s = 0;
    #pragma unroll
    for (int j = 0; j < 8; ++j) {
        int i = base + j;
        int c = (i < N) ? cnt[i] : 0;
        s += c + (c & 1);
    }
    sm[t] = s;
    __syncthreads();
    for (int w = 128; w > 0; w >>= 1) {
        if (t < w) sm[t] += sm[t + w];
        __syncthreads();
    }
    if (t == 0) partials[blockIdx.x] = sm[0];
}

__global__ __launch_bounds__(256) void scanB_kernel(
    int* __restrict__ partials, int* __restrict__ row, int N, int NB)
{
    __shared__ int sm[256];
    int t = threadIdx.x;
    int i0 = t * 4;
    int a0 = (i0 + 0 < NB) ? partials[i0 + 0] : 0;
    int a1 = (i0 + 1 < NB) ? partials[i0 + 1] : 0;
    int a2 = (i0 + 2 < NB) ? partials[i0 + 2] : 0;
    int a3 = (i0 + 3 < NB) ? partials[i0 + 3] : 0;
    int ts = a0 + a1 + a2 + a3;
    sm[t] = ts;
    __syncthreads();
    for (int o = 1; o < 256; o <<= 1) {
        int x = (t >= o) ? sm[t - o] : 0;
        __syncthreads();
        sm[t] += x;
        __syncthreads();
    }
    int ex = sm[t] - ts;
    if (i0 + 0 < NB) partials[i0 + 0] = ex; ex += a0;
    if (i0 + 1 < NB) partials[i0 + 1] = ex; ex += a1;
    if (i0 + 2 < NB) partials[i0 + 2] = ex; ex += a2;
    if (i0 + 3 < NB) partials[i0 + 3] = ex;
    if (t == 255) row[N] = sm[255];
}

// scanC + fused initz (bvec, z0, pad-slot zero)
__global__ __launch_bounds__(256) void scanC_kernel(
    const int* __restrict__ cnt, const int* __restrict__ partials,
    int* __restrict__ row, int* __restrict__ ofs,
    const unsigned char* __restrict__ m8, const int* __restrict__ m32,
    const int* __restrict__ msum,
    Rec* __restrict__ recs,
    double* __restrict__ bvec, double* __restrict__ z0,
    int N)
{
    __shared__ int sm[256];
    int t = threadIdx.x;
    int base = blockIdx.x * 2048 + t * 8;
    int vals[8];
    int s = 0;
    #pragma unroll
    for (int j = 0; j < 8; ++j) {
        int i = base + j;
        int c = (i < N) ? cnt[i] : 0;
        vals[j] = c + (c & 1);
        s += vals[j];
    }
    sm[t] = s;
    __syncthreads();
    for (int o = 1; o < 256; o <<= 1) {
        int x = (t >= o) ? sm[t - o] : 0;
        __syncthreads();
        sm[t] += x;
        __syncthreads();
    }
    int ex = sm[t] - s + partials[blockIdx.x];
    bool bytemask = (*msum == 1);
    #pragma unroll
    for (int j = 0; j < 8; ++j) {
        int i = base + j;
        if (i < N) {
            row[i] = ex; ofs[i] = ex;
            double b = bytemask ? ((m8[i] != 0) ? 1.0 : 0.0)
                                : ((m32[i] != 0) ? 1.0 : 0.0);
            bvec[i] = b;
            z0[i]   = b;
            int c = cnt[i];
            if (c & 1) {                          // zero single pad slot
                Rec zr; zr.r = 0.0f; zr.dst = 0;
                recs[ex + c] = zr;
            }
        }
        ex += vals[j];
    }
}

// XCD-partitioned scatter (proven round 12)
__global__ __launch_bounds__(256) void scatter_kernel(
    const int* __restrict__ src, const int* __restrict__ dst,
    const float* __restrict__ r, int* __restrict__ ofs,
    Rec* __restrict__ recs, int E, int N)
{
    int part  = blockIdx.x & 7;
    int bslot = blockIdx.x >> 3;
    int nbs   = gridDim.x >> 3;
    int lo = (int)(((long)part * N) >> 3);
    int hi = (int)(((long)(part + 1) * N) >> 3);
    int tid = bslot * blockDim.x + threadIdx.x;
    int stride = nbs * blockDim.x;
    for (int e = tid; e < E; e += stride) {
        int s = src[e];
        if (s >= lo && s < hi) {
            int p = atomicAdd(&ofs[s], 1);
            Rec rc; rc.r = r[e]; rc.dst = dst[e];
            recs[p] = rc;
        }
    }
}

// ---------------- gather: 4 lanes/node, dual-pair ILP (proven round 12) -----
__global__ __launch_bounds__(256) void gather4_kernel(
    const int* __restrict__ row,
    const float4* __restrict__ recs4,
    const double* __restrict__ zin,
    double* __restrict__ zout,
    const double* __restrict__ bvec,
    float* __restrict__ out_logz,
    int N, int writeLog)
{
    int g = blockIdx.x * blockDim.x + threadIdx.x;
    int node = g >> 2;
    int sub  = g & 3;
    if (node >= N) return;

    int pbeg = row[node] >> 1, pend = row[node + 1] >> 1;
    double acc = 0.0;
    int p0 = pbeg + sub;
    while (p0 < pend) {
        int p1 = p0 + 4;
        float4 q0 = recs4[p0];
        if (p1 < pend) {
            float4 q1 = recs4[p1];
            acc += (double)q0.x * zin[__float_as_int(q0.y)]
                 + (double)q0.z * zin[__float_as_int(q0.w)]
                 + (double)q1.x * zin[__float_as_int(q1.y)]
                 + (double)q1.z * zin[__float_as_int(q1.w)];
        } else {
            acc += (double)q0.x * zin[__float_as_int(q0.y)]
                 + (double)q0.z * zin[__float_as_int(q0.w)];
        }
        p0 += 8;
    }
    acc += __shfl_down(acc, 2, 4);
    acc += __shfl_down(acc, 1, 4);
    if (sub == 0) {
        double v = bvec[node] + acc;
        zout[node] = v;
        if (writeLog) out_logz[node] = (float)log(v);
    }
}

// ---------------- final: edge probs (out2, in-place over r) -----------------
__global__ __launch_bounds__(256) void final2_kernel(
    const int* __restrict__ src, const int* __restrict__ dst,
    const float* __restrict__ out_logz,
    float* probs_r, int E)
{
    int e = blockIdx.x * blockDim.x + threadIdx.x;
    if (e >= E) return;
    float rr = probs_r[e];
    float p  = rr * expf(out_logz[dst[e]] - out_logz[src[e]]);
    probs_r[e] = p;
}

// ---------------- launch -----------------------------------------------------
extern "C" void kernel_launch(void* const* d_in, const int* in_sizes, int n_in,
                              void* d_out, int out_size, void* d_ws, size_t ws_size,
                              hipStream_t stream)
{
    const int*           edge_index = (const int*)d_in[0];   // [2, E] = [src; dst]
    const float*         X          = (const float*)d_in[1];
    const unsigned char* mask8      = (const unsigned char*)d_in[2];
    const int*           mask32     = (const int*)d_in[2];
    const float*         W1         = (const float*)d_in[3];
    const float*         b1         = (const float*)d_in[4];
    const float*         W2         = (const float*)d_in[5];
    const float*         b2         = (const float*)d_in[6];

    const int E = in_sizes[0] / 2;
    const int N = in_sizes[2];
    const int* src = edge_index;
    const int* dst = edge_index + E;

    float* out      = (float*)d_out;
    float* out_logr = out;
    float* out_logz = out + E;
    float* out_pr   = out + (size_t)E + N;       // r scratch, then probs

    // --- workspace carve-out ---
    char* ws = (char*)d_ws;
    size_t off = 0;
    auto alloc = [&](size_t bytes) -> char* {
        char* p = ws + off;
        off = (off + bytes + 255) & ~(size_t)255;
        return p;
    };
    const int RECS = E + N;
    int*    msum  = (int*)   alloc(4);
    int*    parts = (int*)   alloc(4096);
    int*    cnt   = (int*)   alloc((size_t)N * 4);
    int*    ofs   = (int*)   alloc((size_t)N * 4);
    int*    row   = (int*)   alloc(((size_t)N + 1) * 4);
    Rec*    recs  = (Rec*)   alloc((size_t)RECS * 8);
    double* bvec  = (double*)alloc((size_t)N * 8);
    double* z0    = (double*)alloc((size_t)N * 8);
    double* z1    = (double*)alloc((size_t)N * 8);
    (void)ws_size;

    hipMemsetAsync(msum, 0, 4, stream);
    detect2_kernel<<<128, 256, 0, stream>>>(mask8, N, msum, cnt);
    encoder_kernel<<<(E + 255) / 256, 256, 0, stream>>>(
        X, W1, b1, W2, b2, src, cnt, out_logr, out_pr, E);

    // ---- CSR build: multi-block scan (+ fused init) ----
    const int NB = (N + 2047) / 2048;
    scanA_kernel<<<NB, 256, 0, stream>>>(cnt, parts, N);
    scanB_kernel<<<1, 256, 0, stream>>>(parts, row, N, NB);
    scanC_kernel<<<NB, 256, 0, stream>>>(
        cnt, parts, row, ofs, mask8, mask32, msum, recs, bvec, z0, N);

    scatter_kernel<<<2048, 256, 0, stream>>>(
        src, dst, out_pr, ofs, recs, E, N);

    // ---- 50 gather iterations ----
    double* zb[2] = { z0, z1 };
    const int ggrid = (int)((4L * N + 255) / 256);
    for (int k = 0; k < ITERS; ++k) {
        gather4_kernel<<<ggrid, 256, 0, stream>>>(
            row, (const float4*)recs, zb[k & 1], zb[(k + 1) & 1], bvec,
            out_logz, N, (k == ITERS - 1) ? 1 : 0);
    }

    final2_kernel<<<(E + 255) / 256, 256, 0, stream>>>(
        src, dst, out_logz, out_pr, E);
}